// Round 16
// baseline (192.380 us; speedup 1.0000x reference)
//
#include <hip/hip_runtime.h>
#include <hip/hip_bf16.h>
#include <math.h>

#define HH 80
#define WW 80
#define NPIX 6400
#define LL 21
#define NITER 5
#define C_LOG2E 1.44269504088896f

// bilateral MFMA kernel geometry (SJ=320; LDS 30.1KB -> 5 blocks/CU)
#define SJ  320             // j-slice per block
#define CHK (SJ / 32)       // 10 chunks of 32 j
#define QROW 164            // Q LDS row stride in u32 (320 bf16 + pad)
#define QROWS 22            // rows 0..20 labels, 21 = ones; lanes m>=22 alias row 0
#define NBLK 1000           // 50 x 20 tiles; <= 5/CU x 256 = 1280 slots, one round
#define NBY  20             // j0 slices (partial-accumulator count)
#define NLP  11             // packed row-pairs (22 rows -> 11 u32 rows)
#define SPWORK (LL * NPIX)  // 134400 spat_x pixel-rows, uniform over blocks

// merged spat_y+reduce+combine kernel geometry
#define PXB 16              // pixels per block
#define SYB (NPIX / PXB)    // 400 blocks
#define SYT 384             // 6 waves

typedef short short8 __attribute__((ext_vector_type(8)));
typedef float f32x16 __attribute__((ext_vector_type(16)));

__device__ inline ushort bf_rne(float x) {
    uint u = __float_as_uint(x);
    return (ushort)((u + 0x7FFFu + ((u >> 16) & 1u)) >> 16);
}
__device__ inline float bf_to_f(ushort h) { return __uint_as_float(((uint)h) << 16); }
__device__ inline uint pk2(float a, float b) {
    __hip_bfloat162 t = __float22bfloat162_rn(make_float2(a, b));
    return *reinterpret_cast<uint*>(&t);
}
// 1-op RTZ pack for E (per-j error cancels in the bi/norm ratio)
__device__ inline uint pk2z(float a, float b) {
    return __builtin_amdgcn_perm(__float_as_uint(b), __float_as_uint(a), 0x07060302u);
}
__device__ inline float fexp2(float x) { return __builtin_amdgcn_exp2f(x); }

// ================ setup: blocks 0..24 = pre+softmax0, block 25 = mats
// A-row (j): [h0..h4, l2,l3,l4, h2,h3,h4, l2,l3,l4, mjh, mjl]  (mhs_j folded in)
// B-row (i): [H0..H4, H2,H3,H4, L2,L3,L4, L2,L3,L4, 1.0, 1.0]
//   => D1 = log2e*(fi.fj) + mhs_j  (rgb product exact; mhs_i added in VALU)
__global__ void k_setup(const float* __restrict__ img, const float* __restrict__ unary,
                        const float* __restrict__ Wsp, const float* __restrict__ Wbi,
                        const float* __restrict__ C, ushort* __restrict__ fjg,
                        uint* __restrict__ fig, float* __restrict__ mhs,
                        float* __restrict__ nsp, ushort* __restrict__ qb16,
                        float* __restrict__ M1, float* __restrict__ M2) {
    int tid = threadIdx.x;
    if (blockIdx.x == 25) {           // ---- mats role
        for (int t = tid; t < LL * LL; t += 256) {
            int l = t / LL, k = t % LL;
            float a = 0.f, b = 0.f;
            for (int m = 0; m < LL; m++) {
                a += C[l * LL + m] * Wsp[m * LL + k];
                b += C[l * LL + m] * Wbi[m * LL + k];
            }
            M1[t] = a; M2[t] = b;
        }
        return;
    }
    __shared__ float sxT[WW];
    if (tid < WW) {
        float s = 0.f;
        for (int t = 0; t < WW; t++) { float d = (float)(tid - t); s += __expf(-d * d * (1.0f / 18.0f)); }
        sxT[tid] = s;
    }
    __syncthreads();
    int i = blockIdx.x * 256 + tid;
    int x = i % WW, y = i / WW;
    float f[5];
    f[0] = (float)x * (1.0f / 160.0f);
    f[1] = (float)y * (1.0f / 160.0f);
    f[2] = (img[0 * NPIX + i] - 127.5f) * (1.0f / 3.0f);
    f[3] = (img[1 * NPIX + i] - 127.5f) * (1.0f / 3.0f);
    f[4] = (img[2 * NPIX + i] - 127.5f) * (1.0f / 3.0f);
    float s = 0.f;
    ushort hi[5], lo[5], Hi[5], Lo[5];
#pragma unroll
    for (int c = 0; c < 5; c++) {
        s += f[c] * f[c];
        hi[c] = bf_rne(f[c]);
        lo[c] = bf_rne(f[c] - bf_to_f(hi[c]));
        float a = C_LOG2E * f[c];
        Hi[c] = bf_rne(a);
        Lo[c] = bf_rne(a - bf_to_f(Hi[c]));
    }
    float mi = -0.5f * C_LOG2E * s;
    mhs[i] = mi;
    ushort mjh = bf_rne(mi);
    ushort mjl = bf_rne(mi - bf_to_f(mjh));
    {   // A-side row (with mhs_j in slots 14/15)
        ushort r0[16] = { hi[0], hi[1], hi[2], hi[3], hi[4], lo[2], lo[3], lo[4],
                          hi[2], hi[3], hi[4], lo[2], lo[3], lo[4], mjh, mjl };
        uint4 w0, w1;
        w0.x = (uint)r0[0] | ((uint)r0[1] << 16);  w0.y = (uint)r0[2] | ((uint)r0[3] << 16);
        w0.z = (uint)r0[4] | ((uint)r0[5] << 16);  w0.w = (uint)r0[6] | ((uint)r0[7] << 16);
        w1.x = (uint)r0[8] | ((uint)r0[9] << 16);  w1.y = (uint)r0[10] | ((uint)r0[11] << 16);
        w1.z = (uint)r0[12] | ((uint)r0[13] << 16); w1.w = (uint)r0[14] | ((uint)r0[15] << 16);
        *(uint4*)(fjg + (size_t)i * 16) = w0;
        *(uint4*)(fjg + (size_t)i * 16 + 8) = w1;
    }
    {   // B-side row (slots 14/15 = 1.0 to pass mjh+mjl through)
        ushort r1[16] = { Hi[0], Hi[1], Hi[2], Hi[3], Hi[4], Hi[2], Hi[3], Hi[4],
                          Lo[2], Lo[3], Lo[4], Lo[2], Lo[3], Lo[4], 0x3F80, 0x3F80 };
        uint4 w0, w1;
        w0.x = (uint)r1[0] | ((uint)r1[1] << 16);  w0.y = (uint)r1[2] | ((uint)r1[3] << 16);
        w0.z = (uint)r1[4] | ((uint)r1[5] << 16);  w0.w = (uint)r1[6] | ((uint)r1[7] << 16);
        w1.x = (uint)r1[8] | ((uint)r1[9] << 16);  w1.y = (uint)r1[10] | ((uint)r1[11] << 16);
        w1.z = (uint)r1[12] | ((uint)r1[13] << 16); w1.w = (uint)r1[14] | ((uint)r1[15] << 16);
        *(uint4*)(fig + (size_t)i * 8) = w0;
        *(uint4*)(fig + (size_t)i * 8 + 4) = w1;
    }
    nsp[i] = 1.0f / (sxT[x] * sxT[y] + 1e-8f);
    float v[LL];
    float mx = -1e30f;
    for (int l = 0; l < LL; l++) { v[l] = unary[l * NPIX + i]; mx = fmaxf(mx, v[l]); }
    float ss = 0.f;
    for (int l = 0; l < LL; l++) { v[l] = __expf(v[l] - mx); ss += v[l]; }
    float r = 1.0f / ss;
    for (int l = 0; l < LL; l++) qb16[(size_t)l * NPIX + i] = bf_rne(v[l] * r);
}

// ================ iteration kernel 1: 1000 blocks, one co-residency round.
// K-loop LDS = 3 b128/chunk (af + qa + qb); mhs_j rides the A-row, mhs_i in VALU.
// bip partials packed bf16x2. Uniform ~134-px spat_x rider (packed u32 reads).
__global__ __launch_bounds__(256, 5)
void k_iter1(const float* __restrict__ mhs, const ushort* __restrict__ fjg,
             const uint* __restrict__ fig, const ushort* __restrict__ qb16,
             uint* __restrict__ bip, ushort* __restrict__ tmpx) {
    __shared__ __align__(16) uint  FjL[SJ * 12];
    __shared__ __align__(16) uint  QL[QROWS * QROW];
    __shared__ float gT[WW];
    int tid = threadIdx.x;
    int bid = blockIdx.x;
    int bx = bid % 50, by = bid / 50;
    int j0 = by * SJ;
    // ---- stage Q first (most global-load latency to hide)
    for (int idx = tid; idx < QROWS * (SJ / 2); idx += 256) {
        int l = idx / (SJ / 2), jp = idx % (SJ / 2);
        uint v;
        if (l < LL) {
            const uint* p = (const uint*)qb16 + (((size_t)l * NPIX + j0) >> 1);
            v = p[jp];
        } else {
            v = 0x3F803F80u;
        }
        QL[l * QROW + jp] = v;
    }
    for (int idx = tid; idx < SJ * 2; idx += 256) {
        int r = idx >> 1, hf = idx & 1;
        uint4 v = ((const uint4*)(fjg + (size_t)(j0 + r) * 16))[hf];
        *(uint4*)&FjL[r * 12 + hf * 4] = v;
    }
    if (tid < WW) gT[tid] = __expf(-(float)(tid * tid) * (1.0f / 18.0f));
    int lane = tid & 63, wid = tid >> 6;
    int h = lane >> 5, m = lane & 31;
    int i = bx * 128 + wid * 32 + m;
    union U8 { uint u[4]; short8 s; };
    U8 bfr;
    {
        uint4 bv = *(const uint4*)(fig + (size_t)i * 8 + h * 4);
        bfr.u[0] = bv.x; bfr.u[1] = bv.y; bfr.u[2] = bv.z; bfr.u[3] = bv.w;
    }
    float mi = mhs[i];
    int jrow = (m & ~12) | ((m & 4) << 1) | ((m & 8) >> 1);
    int qrow = (m < QROWS) ? m : 0;
    __syncthreads();
    f32x16 acc, zc;
#pragma unroll
    for (int k = 0; k < 16; k++) { acc[k] = 0.f; zc[k] = 0.f; }
    const uint* qbase = &QL[qrow * QROW + h * 4];
    for (int c = 0; c < CHK; c++) {
        int jb = c * 32;
        short8 af = *(const short8*)&FjL[(jb + jrow) * 12 + h * 4];
        f32x16 d1 = __builtin_amdgcn_mfma_f32_32x32x16_bf16(af, bfr.s, zc, 0, 0, 0);
        short8 qa = *(const short8*)(qbase + c * 16);
        short8 qb = *(const short8*)(qbase + c * 16 + 8);
        U8 ea;
        ea.u[0] = pk2z(fexp2(d1[0] + mi), fexp2(d1[1] + mi));
        ea.u[1] = pk2z(fexp2(d1[2] + mi), fexp2(d1[3] + mi));
        ea.u[2] = pk2z(fexp2(d1[4] + mi), fexp2(d1[5] + mi));
        ea.u[3] = pk2z(fexp2(d1[6] + mi), fexp2(d1[7] + mi));
        acc = __builtin_amdgcn_mfma_f32_32x32x16_bf16(qa, ea.s, acc, 0, 0, 0);
        U8 eb;
        eb.u[0] = pk2z(fexp2(d1[8]  + mi), fexp2(d1[9]  + mi));
        eb.u[1] = pk2z(fexp2(d1[10] + mi), fexp2(d1[11] + mi));
        eb.u[2] = pk2z(fexp2(d1[12] + mi), fexp2(d1[13] + mi));
        eb.u[3] = pk2z(fexp2(d1[14] + mi), fexp2(d1[15] + mi));
        acc = __builtin_amdgcn_mfma_f32_32x32x16_bf16(qb, eb.s, acc, 0, 0, 0);
    }
    // ---- epilogue: pack adjacent-l pairs into bf16x2 partials
#pragma unroll
    for (int r = 0; r < 16; r += 2) {
        int l = (r & 3) + 8 * (r >> 2) + 4 * h;    // even l of the pair
        if (l < LL + 1)
            bip[((size_t)by * NLP + (l >> 1)) * NPIX + i] = pk2(acc[r], acc[r + 1]);
    }
    // ---- spat_x rider: uniform ~134-px slice; packed u32 reads, bf16 store
    {
        int start = (int)(((long)bid * SPWORK) / NBLK);
        int end   = (int)(((long)(bid + 1) * SPWORK) / NBLK);
        int cnt = end - start;
        if (tid < cnt) {
            int fidx = start + tid;
            int l = fidx / NPIX;
            int p = fidx - l * NPIX;
            int x = p % WW, y = p / WW;
            const uint* rowq = (const uint*)(qb16 + (size_t)l * NPIX + y * WW);
            float s = 0.f;
            for (int k = 0; k < WW / 2; k++) {
                uint v = rowq[k];
                int d0 = x - 2 * k;     d0 = d0 < 0 ? -d0 : d0;
                int d1 = x - 2 * k - 1; d1 = d1 < 0 ? -d1 : d1;
                s += gT[d0] * __uint_as_float(v << 16);
                s += gT[d1] * __uint_as_float(v & 0xFFFF0000u);
            }
            tmpx[(size_t)l * NPIX + p] = bf_rne(s);
        }
    }
}

// ================ iteration kernel 2 (merged): spat_y + reduce + combine + softmax
// 400 blocks x 384 thr; block owns ALL rows of its 16 pixels.
__global__ __launch_bounds__(SYT)
void k_syc(const float* __restrict__ unary, const ushort* __restrict__ tmpx,
           const uint* __restrict__ bip, const float* __restrict__ nsp,
           const float* __restrict__ M1, const float* __restrict__ M2,
           ushort* __restrict__ qb16, float* __restrict__ out, int last) {
    __shared__ float m1s[LL * 24];
    __shared__ float m2s[LL * 24];
    __shared__ float gT[HH];
    __shared__ float svL[PXB][QROWS];   // [pxl][l] spatial (l<21)
    __shared__ float bvL[PXB][QROWS];   // [pxl][l] bilat reduce (l<=21)
    __shared__ float aex[PXB][QROWS];   // [pxl][l] combined logits
    int tid = threadIdx.x;
    int px0 = blockIdx.x * PXB;
    for (int t = tid; t < LL * LL; t += SYT) {
        int l = t / LL, k = t % LL;
        m1s[l * 24 + k] = M1[t];
        m2s[l * 24 + k] = M2[t];
    }
    if (tid < HH) gT[tid] = __expf(-(float)(tid * tid) * (1.0f / 18.0f));
    __syncthreads();
    // ---- phase A1: spat_y conv, 16 px x 21 labels = 336 tasks (bf16 tmpx)
    if (tid < PXB * LL) {
        int pxl = tid & (PXB - 1);
        int l = tid >> 4;
        int px = px0 + pxl;
        int x = px % WW, y = px / WW;
        const ushort* base = tmpx + (size_t)l * NPIX + x;
        float s1 = 0.f;
        for (int yp = 0; yp < HH; yp++) {
            int d = y - yp; d = d < 0 ? -d : d;
            s1 += gT[d] * bf_to_f(base[yp * WW]);
        }
        svL[pxl][l] = s1;
    }
    // ---- phase A2: packed bip reduce, 16 px x 11 row-pairs = 176 tasks
    if (tid < PXB * NLP) {
        int pxl = tid & (PXB - 1);
        int lp = tid >> 4;
        int px = px0 + pxl;
        float sa = 0.f, sb = 0.f;
        const uint* p = bip + (size_t)lp * NPIX + px;
#pragma unroll
        for (int byi = 0; byi < NBY; byi++) {
            uint v = p[(size_t)byi * NLP * NPIX];
            sa += __uint_as_float(v << 16);
            sb += __uint_as_float(v & 0xFFFF0000u);
        }
        bvL[pxl][2 * lp] = sa;
        bvL[pxl][2 * lp + 1] = sb;
    }
    __syncthreads();
    // ---- phase B1: combine  a[l] = unary + ns*(M1.sv) + nb*(M2.bv)
    if (tid < PXB * LL) {
        int pxl = tid & (PXB - 1);
        int l = tid >> 4;             // 0..20
        int px = px0 + pxl;
        float ns = nsp[px];
        float nb = 1.0f / (bvL[pxl][LL] + 1e-8f);
        float s1 = 0.f, s2 = 0.f;
        const float* r1 = &m1s[l * 24];
        const float* r2 = &m2s[l * 24];
#pragma unroll
        for (int k = 0; k < LL; k++) {
            s1 = fmaf(r1[k], svL[pxl][k], s1);
            s2 = fmaf(r2[k], bvL[pxl][k], s2);
        }
        float a = unary[l * NPIX + px] + ns * s1 + nb * s2;
        if (last) out[(size_t)l * NPIX + px] = a;
        else      aex[pxl][l] = a;
    }
    if (last) return;
    __syncthreads();
    // ---- phase B2: per-pixel softmax -> qb16
    if (tid < PXB) {
        int px = px0 + tid;
        float mx = -1e30f;
        for (int l = 0; l < LL; l++) mx = fmaxf(mx, aex[tid][l]);
        float s = 0.f;
        float e[LL];
        for (int l = 0; l < LL; l++) { e[l] = __expf(aex[tid][l] - mx); s += e[l]; }
        float r = 1.0f / s;
        for (int l = 0; l < LL; l++)
            qb16[(size_t)l * NPIX + px] = bf_rne(e[l] * r);
    }
}

extern "C" void kernel_launch(void* const* d_in, const int* in_sizes, int n_in,
                              void* d_out, int out_size, void* d_ws, size_t ws_size,
                              hipStream_t stream) {
    const float* img   = (const float*)d_in[0];
    const float* unary = (const float*)d_in[1];
    const float* Wsp   = (const float*)d_in[2];
    const float* Wbi   = (const float*)d_in[3];
    const float* C     = (const float*)d_in[4];
    float* out = (float*)d_out;

    const int LN = LL * NPIX;
    float* w = (float*)d_ws;
    ushort* tmpx = (ushort*)w;  w += (LN + 1) / 2;      // spat_x out, bf16
    uint*   bip  = (uint*)w;    w += NBY * NLP * NPIX;  // packed bf16x2 partials
    float*  mhs  = w;  w += NPIX;
    float*  nsp  = w;  w += NPIX;
    ushort* fjg  = (ushort*)w;  w += 8 * NPIX;          // A-rows [N][16 bf16]
    uint*   fig  = (uint*)w;    w += 8 * NPIX;          // B-rows [N][8 u32]
    ushort* qb16 = (ushort*)w;  w += (LN + 1) / 2;      // Q in bf16 [21][N]
    float*  M1   = w;  w += LL * LL;
    float*  M2   = w;  w += LL * LL;

    k_setup<<<26, 256, 0, stream>>>(img, unary, Wsp, Wbi, C, fjg, fig, mhs, nsp,
                                    qb16, M1, M2);
    for (int it = 0; it < NITER; it++) {
        int last = (it == NITER - 1);
        k_iter1<<<NBLK, 256, 0, stream>>>(mhs, fjg, fig, qb16, bip, tmpx);
        k_syc<<<SYB, SYT, 0, stream>>>(unary, tmpx, bip, nsp, M1, M2, qb16, out, last);
    }
}